// Round 8
// baseline (79.073 us; speedup 1.0000x reference)
//
#include <hip/hip_runtime.h>
#include <hip/hip_bf16.h>
#include <math.h>

#define H 256
#define L_SEQ 131072
#define NBLK 1024           // attention blocks (power of two)
#define RPB (L_SEQ / NBLK)  // 128 rows per block

__device__ __forceinline__ float wave_reduce_sum(float v) {
#pragma unroll
  for (int off = 32; off > 0; off >>= 1) v += __shfl_xor(v, off, 64);
  return v;
}

// One fused kernel: 1024 blocks scan E with online exp-sum attention;
// blocks 0..255 also compute ghh2 = W_hh@h + b + W_ih[:,0:40]@emb and
// transpose W_ih[:,40:50]; blocks 256..271 warm L3 with head weights.
// The LAST block to finish (atomic vote, mod-1024 so no counter reset
// needed) runs the entire tail: combine -> ctx10 -> gates -> LSTM -> heads.
__global__ __launch_bounds__(256, 4) void k1_fused(
    const float* __restrict__ E, const float* __restrict__ h,
    const float* __restrict__ attn_W, const float* __restrict__ W_hh,
    const float* __restrict__ b_ih, const float* __restrict__ b_hh,
    const float* __restrict__ W_ih,
    const float* __restrict__ chord_emb, const float* __restrict__ pitch_emb,
    const float* __restrict__ dur_emb,
    const int* __restrict__ sec_p, const int* __restrict__ chord_p,
    const int* __restrict__ tp_p, const int* __restrict__ note_p,
    const float* __restrict__ attn_b, const float* __restrict__ c_in,
    const float* __restrict__ pitch_W, const float* __restrict__ pitch_b,
    const float* __restrict__ dur_W, const float* __restrict__ dur_b,
    float* __restrict__ p10, float* __restrict__ ghh2,
    float* __restrict__ WcT, float* __restrict__ dummy,
    unsigned* __restrict__ cnt, float* __restrict__ out) {
  const int b = blockIdx.x;
  const int t = threadIdx.x;
  const int lane = t & 63;
  const int w = t >> 6;
  const float4 hreg = reinterpret_cast<const float4*>(h)[lane];

  // ---- attention chunk: fixed M=0 exp-sum, 8-row unroll ----
  float s = 0.f;
  float4 acc = make_float4(0.f, 0.f, 0.f, 0.f);
  const float4* E4 = reinterpret_cast<const float4*>(E);
  const size_t base = (size_t)b * RPB;
#pragma unroll
  for (int k = 0; k < RPB / 32; ++k) {
    const int r = w * 8 + 32 * k;
    float4 e[8];
#pragma unroll
    for (int j = 0; j < 8; ++j) e[j] = E4[(base + r + j) * 64 + lane];
    float d[8];
#pragma unroll
    for (int j = 0; j < 8; ++j)
      d[j] = e[j].x * hreg.x + e[j].y * hreg.y + e[j].z * hreg.z + e[j].w * hreg.w;
#pragma unroll
    for (int off = 32; off > 0; off >>= 1) {
#pragma unroll
      for (int j = 0; j < 8; ++j) d[j] += __shfl_xor(d[j], off, 64);
    }
#pragma unroll
    for (int j = 0; j < 8; ++j) {
      const float wj = __expf(d[j]);
      s += wj;
      acc.x += wj * e[j].x;
      acc.y += wj * e[j].y;
      acc.z += wj * e[j].z;
      acc.w += wj * e[j].w;
    }
  }
  __shared__ float ss[4];
  __shared__ float4 sacc4[4][64];
  sacc4[w][lane] = acc;
  if (lane == 0) ss[w] = s;
  __syncthreads();
  __shared__ float ctx_s[H];
  {
    const float* sf = reinterpret_cast<const float*>(sacc4);
    ctx_s[t] = (sf[t] + sf[256 + t]) + (sf[512 + t] + sf[768 + t]);
  }
  __syncthreads();
  {
    const float4 c4 = reinterpret_cast<const float4*>(ctx_s)[lane];
    for (int row = w; row < 10; row += 4) {
      const float4 a4 = reinterpret_cast<const float4*>(attn_W + row * H)[lane];
      float d = c4.x * a4.x + c4.y * a4.y + c4.z * a4.z + c4.w * a4.w;
      d = wave_reduce_sum(d);
      if (lane == 0) p10[row * NBLK + b] = d;
    }
  }
  if (t == 0) p10[10 * NBLK + b] = (ss[0] + ss[1]) + (ss[2] + ss[3]);

  // ---- side work ----
  if (b < 256) {
    const int r = b * 4 + w;  // gate row
    const float4 wv = reinterpret_cast<const float4*>(W_hh + (size_t)r * H)[lane];
    float d = wv.x * hreg.x + wv.y * hreg.y + wv.z * hreg.z + wv.w * hreg.w;
    if (lane < 50) {
      const float wih = W_ih[r * 50 + lane];
      if (lane < 40) {
        int idx; const float* tbl;
        if (lane < 10)      { tbl = pitch_emb; idx = note_p[0] * 10 + lane; }
        else if (lane < 20) { tbl = dur_emb;   idx = note_p[1] * 10 + lane - 10; }
        else if (lane < 30) { tbl = chord_emb; idx = chord_p[0] * 10 + lane - 20; }
        else                { tbl = chord_emb; idx = sec_p[0] * 10 + lane - 30; }
        d += wih * tbl[idx];
      } else {
        WcT[(lane - 40) * NBLK + r] = wih;  // transpose cols 40..49
      }
    }
    d = wave_reduce_sum(d);
    if (lane == 0) ghh2[r] = d + b_ih[r] + b_hh[r];
  } else if (b < 272) {
    const int slice = b - 256;  // warm L3 for the tail
    float a = 0.f;
    const float4* pw4 = reinterpret_cast<const float4*>(pitch_W);
    for (int i = slice * 256 + t; i < 4032; i += 16 * 256) {
      float4 v = pw4[i]; a += v.x + v.y + v.z + v.w;
    }
    const float4* dw4 = reinterpret_cast<const float4*>(dur_W);
    for (int i = slice * 256 + t; i < 1064; i += 16 * 256) {
      float4 v = dw4[i]; a += v.x + v.y + v.z + v.w;
    }
    a = wave_reduce_sum(a);
    if (lane == 0) dummy[slice * 4 + w] = a;
  }

  // ---- completion vote: exactly one winner per call, any counter start ----
  __syncthreads();
  __shared__ unsigned oldsh;
  if (t == 0) {
    __threadfence();  // release: make this block's ws stores visible
    oldsh = __hip_atomic_fetch_add(cnt, 1u, __ATOMIC_ACQ_REL,
                                   __HIP_MEMORY_SCOPE_AGENT);
  }
  __syncthreads();
  if ((oldsh & (NBLK - 1u)) != (NBLK - 1u)) return;
  if (t == 0) __threadfence();  // acquire: see all other blocks' stores
  __syncthreads();

  // ---- tail (winner block only, 4 waves) ----
  __shared__ float red[11];
  __shared__ float ctxsh[10];
  __shared__ float gsh[1024];
  __shared__ float hsh[H];
  __shared__ float etsh[16];
  for (int col = w; col < 11; col += 4) {
    const float4* pc = reinterpret_cast<const float4*>(p10 + col * NBLK);
    float v = 0.f;
#pragma unroll
    for (int i = 0; i < 4; ++i) {
      const float4 a = pc[lane + 64 * i];
      v += (a.x + a.y) + (a.z + a.w);
    }
    v = wave_reduce_sum(v);
    if (lane == 0) red[col] = v;
  }
  if (t < 10) etsh[t] = pitch_emb[tp_p[0] * 10 + t];
  __syncthreads();
  if (t < 10) ctxsh[t] = red[t] / red[10] + attn_b[t];
  __syncthreads();
#pragma unroll
  for (int i = 0; i < 4; ++i) {
    const int r = t + 256 * i;
    float g = ghh2[r];
#pragma unroll
    for (int c = 0; c < 10; ++c) g += WcT[c * NBLK + r] * ctxsh[c];
    gsh[r] = g;
  }
  __syncthreads();
  {
    const float i_s = 1.f / (1.f + __expf(-gsh[t]));
    const float f_s = 1.f / (1.f + __expf(-gsh[256 + t]));
    const float g_t = tanhf(gsh[512 + t]);
    const float o_s = 1.f / (1.f + __expf(-gsh[768 + t]));
    const float cn = f_s * c_in[t] + i_s * g_t;
    const float hn = o_s * tanhf(cn);
    out[79 + t] = hn;   // h_new at [79, 335)
    out[335 + t] = cn;  // c_new at [335, 591)
    hsh[t] = hn;
  }
  __syncthreads();
  const float4 h4 = reinterpret_cast<const float4*>(hsh)[lane];
  for (int row = w; row < 63; row += 4) {  // pitch head
    const float4 pw = reinterpret_cast<const float4*>(pitch_W + (size_t)row * H)[lane];
    float d = pw.x * h4.x + pw.y * h4.y + pw.z * h4.z + pw.w * h4.w;
    d = wave_reduce_sum(d);
    if (lane == 0) out[row] = d + pitch_b[row];
  }
  for (int row = w; row < 16; row += 4) {  // dur head (concat [e_true, h])
    const float* dw = dur_W + (size_t)row * 266;
    float d = 0.f;
    for (int k = lane; k < 266; k += 64)
      d += dw[k] * (k < 10 ? etsh[k] : hsh[k - 10]);
    d = wave_reduce_sum(d);
    if (lane == 0) out[63 + row] = d + dur_b[row];
  }
}

extern "C" void kernel_launch(void* const* d_in, const int* in_sizes, int n_in,
                              void* d_out, int out_size, void* d_ws, size_t ws_size,
                              hipStream_t stream) {
  const int* sec       = (const int*)d_in[0];
  const int* chord     = (const int*)d_in[1];
  const int* tp        = (const int*)d_in[2];
  const int* note      = (const int*)d_in[3];
  const float* hn      = (const float*)d_in[4];
  const float* cn      = (const float*)d_in[5];
  const float* E       = (const float*)d_in[6];
  const float* chord_e = (const float*)d_in[7];
  const float* pitch_e = (const float*)d_in[8];
  const float* dur_e   = (const float*)d_in[9];
  const float* W_ih    = (const float*)d_in[10];
  const float* W_hh    = (const float*)d_in[11];
  const float* b_ih    = (const float*)d_in[12];
  const float* b_hh    = (const float*)d_in[13];
  const float* pitch_W = (const float*)d_in[14];
  const float* pitch_b = (const float*)d_in[15];
  const float* dur_W   = (const float*)d_in[16];
  const float* dur_b   = (const float*)d_in[17];
  const float* attn_W  = (const float*)d_in[18];
  const float* attn_b  = (const float*)d_in[19];
  float* out = (float*)d_out;
  float* ws = (float*)d_ws;

  float* p10      = ws;               // 11 * 1024
  float* ghh2     = ws + 11 * NBLK;   // 1024
  float* WcT      = ghh2 + 1024;      // 10 * 1024
  float* dummy    = WcT + 10 * NBLK;  // 64
  unsigned* cnt   = (unsigned*)(dummy + 64);  // 1 (never reset; mod-1024 vote)

  k1_fused<<<NBLK, 256, 0, stream>>>(E, hn, attn_W, W_hh, b_ih, b_hh, W_ih,
                                     chord_e, pitch_e, dur_e, sec, chord, tp,
                                     note, attn_b, cn, pitch_W, pitch_b,
                                     dur_W, dur_b, p10, ghh2, WcT, dummy,
                                     cnt, out);
}

// Round 9
// 32.906 us; speedup vs baseline: 2.4030x; 2.4030x over previous
//
#include <hip/hip_runtime.h>
#include <hip/hip_bf16.h>
#include <math.h>

#define H 256
#define L_SEQ 131072
#define NBLK 2048           // attention blocks (power of two)
#define RPB (L_SEQ / NBLK)  // 64 rows per block
#define GROWS 1024          // LSTM gate rows (4H)

__device__ __forceinline__ float wave_reduce_sum(float v) {
#pragma unroll
  for (int off = 32; off > 0; off >>= 1) v += __shfl_xor(v, off, 64);
  return v;
}

// ---- K1: 2048 blocks (8/CU). All: softmax-sum partial (M=0) + attn_W proj.
//      blocks 0..255 also: ghh2 = W_hh@h + b + W_ih[:,0:40]@emb,
//                          transpose W_ih[:,40:50] -> WcT.
//      blocks 256..271 also: warm L3 with head weights.
__global__ __launch_bounds__(256, 8) void k1_attn(
    const float* __restrict__ E, const float* __restrict__ h,
    const float* __restrict__ attn_W, const float* __restrict__ W_hh,
    const float* __restrict__ b_ih, const float* __restrict__ b_hh,
    const float* __restrict__ W_ih,
    const float* __restrict__ chord_emb, const float* __restrict__ pitch_emb,
    const float* __restrict__ dur_emb,
    const int* __restrict__ sec_p, const int* __restrict__ chord_p,
    const int* __restrict__ note_p,
    const float* __restrict__ pitch_W, const float* __restrict__ dur_W,
    float* __restrict__ p10, float* __restrict__ ghh2,
    float* __restrict__ WcT, float* __restrict__ dummy) {
  const int b = blockIdx.x;
  const int t = threadIdx.x;
  const int lane = t & 63;
  const int w = t >> 6;
  const float4 hreg = reinterpret_cast<const float4*>(h)[lane];

  // ---- attention chunk: fixed M=0 exp-sum, 8-row unroll ----
  float s = 0.f;
  float4 acc = make_float4(0.f, 0.f, 0.f, 0.f);
  const float4* E4 = reinterpret_cast<const float4*>(E);
  const size_t base = (size_t)b * RPB;
#pragma unroll
  for (int k = 0; k < RPB / 32; ++k) {
    const int r = w * 8 + 32 * k;
    float4 e[8];
#pragma unroll
    for (int j = 0; j < 8; ++j) e[j] = E4[(base + r + j) * 64 + lane];
    float d[8];
#pragma unroll
    for (int j = 0; j < 8; ++j)
      d[j] = e[j].x * hreg.x + e[j].y * hreg.y + e[j].z * hreg.z + e[j].w * hreg.w;
#pragma unroll
    for (int off = 32; off > 0; off >>= 1) {
#pragma unroll
      for (int j = 0; j < 8; ++j) d[j] += __shfl_xor(d[j], off, 64);
    }
#pragma unroll
    for (int j = 0; j < 8; ++j) {
      const float wj = __expf(d[j]);
      s += wj;
      acc.x += wj * e[j].x;
      acc.y += wj * e[j].y;
      acc.z += wj * e[j].z;
      acc.w += wj * e[j].w;
    }
  }
  __shared__ float ss[4];
  __shared__ float4 sacc4[4][64];
  sacc4[w][lane] = acc;
  if (lane == 0) ss[w] = s;
  __syncthreads();
  __shared__ float ctx_s[H];
  {
    const float* sf = reinterpret_cast<const float*>(sacc4);
    ctx_s[t] = (sf[t] + sf[256 + t]) + (sf[512 + t] + sf[768 + t]);
  }
  __syncthreads();
  {
    const float4 c4 = reinterpret_cast<const float4*>(ctx_s)[lane];
    for (int row = w; row < 10; row += 4) {
      const float4 a4 = reinterpret_cast<const float4*>(attn_W + row * H)[lane];
      float d = c4.x * a4.x + c4.y * a4.y + c4.z * a4.z + c4.w * a4.w;
      d = wave_reduce_sum(d);
      if (lane == 0) p10[row * NBLK + b] = d;
    }
  }
  if (t == 0) p10[10 * NBLK + b] = (ss[0] + ss[1]) + (ss[2] + ss[3]);

  // ---- side work (hides in the drain phase) ----
  if (b < 256) {
    const int r = b * 4 + w;  // gate row
    const float4 wv = reinterpret_cast<const float4*>(W_hh + (size_t)r * H)[lane];
    float d = wv.x * hreg.x + wv.y * hreg.y + wv.z * hreg.z + wv.w * hreg.w;
    if (lane < 50) {
      const float wih = W_ih[r * 50 + lane];
      if (lane < 40) {
        int idx; const float* tbl;
        if (lane < 10)      { tbl = pitch_emb; idx = note_p[0] * 10 + lane; }
        else if (lane < 20) { tbl = dur_emb;   idx = note_p[1] * 10 + lane - 10; }
        else if (lane < 30) { tbl = chord_emb; idx = chord_p[0] * 10 + lane - 20; }
        else                { tbl = chord_emb; idx = sec_p[0] * 10 + lane - 30; }
        d += wih * tbl[idx];
      } else {
        WcT[(lane - 40) * GROWS + r] = wih;  // transpose cols 40..49
      }
    }
    d = wave_reduce_sum(d);
    if (lane == 0) ghh2[r] = d + b_ih[r] + b_hh[r];
  } else if (b < 272) {
    const int slice = b - 256;  // warm L3 for the tail
    float a = 0.f;
    const float4* pw4 = reinterpret_cast<const float4*>(pitch_W);
    for (int i = slice * 256 + t; i < 4032; i += 16 * 256) {
      float4 v = pw4[i]; a += v.x + v.y + v.z + v.w;
    }
    const float4* dw4 = reinterpret_cast<const float4*>(dur_W);
    for (int i = slice * 256 + t; i < 1064; i += 16 * 256) {
      float4 v = dw4[i]; a += v.x + v.y + v.z + v.w;
    }
    a = wave_reduce_sum(a);
    if (lane == 0) dummy[slice * 4 + w] = a;
  }
}

// ---- K2: fused tail, 4 blocks x 1024 thr. Each block redundantly:
//      combine p10 -> ctx10 -> gates -> LSTM; then waves split the head rows.
__global__ __launch_bounds__(1024) void k2_tail(
    const float* __restrict__ p10, const float* __restrict__ ghh2,
    const float* __restrict__ WcT, const float* __restrict__ attn_b,
    const float* __restrict__ c_in,
    const float* __restrict__ pitch_W, const float* __restrict__ pitch_b,
    const float* __restrict__ dur_W, const float* __restrict__ dur_b,
    const float* __restrict__ pitch_emb, const int* __restrict__ tp_p,
    float* __restrict__ out) {
  const int t = threadIdx.x;
  const int lane = t & 63, w = t >> 6;  // 16 waves
  __shared__ float red[11];
  __shared__ float ctxsh[10];
  __shared__ float gsh[1024];
  __shared__ float hsh[H];
  __shared__ float etsh[16];
  if (w < 11) {  // wave w reduces partial column w (2048 values, float4)
    const float4* pc = reinterpret_cast<const float4*>(p10 + w * NBLK);
    float v = 0.f;
#pragma unroll
    for (int i = 0; i < NBLK / 256; ++i) {
      const float4 a = pc[lane + 64 * i];
      v += (a.x + a.y) + (a.z + a.w);
    }
    v = wave_reduce_sum(v);
    if (lane == 0) red[w] = v;
  }
  if (t >= 704 && t < 714) etsh[t - 704] = pitch_emb[tp_p[0] * 10 + (t - 704)];
  __syncthreads();
  if (t < 10) ctxsh[t] = red[t] / red[10] + attn_b[t];
  __syncthreads();
  float g = ghh2[t];
#pragma unroll
  for (int c = 0; c < 10; c++) g += WcT[c * GROWS + t] * ctxsh[c];
  gsh[t] = g;
  __syncthreads();
  if (t < H) {
    const float i_s = 1.f / (1.f + __expf(-gsh[t]));
    const float f_s = 1.f / (1.f + __expf(-gsh[256 + t]));
    const float g_t = tanhf(gsh[512 + t]);
    const float o_s = 1.f / (1.f + __expf(-gsh[768 + t]));
    const float cn = f_s * c_in[t] + i_s * g_t;
    const float hn = o_s * tanhf(cn);
    if (blockIdx.x == 0) {
      out[79 + t] = hn;   // h_new at [79, 335)
      out[335 + t] = cn;  // c_new at [335, 591)
    }
    hsh[t] = hn;
  }
  __syncthreads();
  const int gw = blockIdx.x * 16 + w;  // 64 global waves
  const float4 h4 = reinterpret_cast<const float4*>(hsh)[lane];
  if (gw < 63) {  // pitch head rows
    const float4 pw = reinterpret_cast<const float4*>(pitch_W + (size_t)gw * H)[lane];
    float d = pw.x * h4.x + pw.y * h4.y + pw.z * h4.z + pw.w * h4.w;
    d = wave_reduce_sum(d);
    if (lane == 0) out[gw] = d + pitch_b[gw];
  }
  if (gw >= 48) {  // dur head rows 0..15 (block 3)
    const int row = gw - 48;
    const float* dw = dur_W + (size_t)row * 266;
    float d = 0.f;
    for (int k = lane; k < 266; k += 64)
      d += dw[k] * (k < 10 ? etsh[k] : hsh[k - 10]);
    d = wave_reduce_sum(d);
    if (lane == 0) out[63 + row] = d + dur_b[row];
  }
}

extern "C" void kernel_launch(void* const* d_in, const int* in_sizes, int n_in,
                              void* d_out, int out_size, void* d_ws, size_t ws_size,
                              hipStream_t stream) {
  const int* sec       = (const int*)d_in[0];
  const int* chord     = (const int*)d_in[1];
  const int* tp        = (const int*)d_in[2];
  const int* note      = (const int*)d_in[3];
  const float* hn      = (const float*)d_in[4];
  const float* cn      = (const float*)d_in[5];
  const float* E       = (const float*)d_in[6];
  const float* chord_e = (const float*)d_in[7];
  const float* pitch_e = (const float*)d_in[8];
  const float* dur_e   = (const float*)d_in[9];
  const float* W_ih    = (const float*)d_in[10];
  const float* W_hh    = (const float*)d_in[11];
  const float* b_ih    = (const float*)d_in[12];
  const float* b_hh    = (const float*)d_in[13];
  const float* pitch_W = (const float*)d_in[14];
  const float* pitch_b = (const float*)d_in[15];
  const float* dur_W   = (const float*)d_in[16];
  const float* dur_b   = (const float*)d_in[17];
  const float* attn_W  = (const float*)d_in[18];
  const float* attn_b  = (const float*)d_in[19];
  float* out = (float*)d_out;
  float* ws = (float*)d_ws;

  float* p10   = ws;                  // 11 * NBLK
  float* ghh2  = ws + 11 * NBLK;      // 1024
  float* WcT   = ghh2 + GROWS;        // 10 * 1024
  float* dummy = WcT + 10 * GROWS;    // 64

  k1_attn<<<NBLK, 256, 0, stream>>>(E, hn, attn_W, W_hh, b_ih, b_hh, W_ih,
                                    chord_e, pitch_e, dur_e, sec, chord, note,
                                    pitch_W, dur_W, p10, ghh2, WcT, dummy);
  k2_tail<<<4, 1024, 0, stream>>>(p10, ghh2, WcT, attn_b, cn,
                                  pitch_W, pitch_b, dur_W, dur_b,
                                  pitch_e, tp, out);
}

// Round 10
// 30.249 us; speedup vs baseline: 2.6141x; 1.0878x over previous
//
#include <hip/hip_runtime.h>
#include <hip/hip_bf16.h>
#include <math.h>

#define H 256
#define L_SEQ 131072
#define NBLK 1024           // attention blocks
#define RPB (L_SEQ / NBLK)  // 128 rows per block
#define GROWS 1024          // LSTM gate rows (4H)

__device__ __forceinline__ float wave_reduce_sum(float v) {
#pragma unroll
  for (int off = 32; off > 0; off >>= 1) v += __shfl_xor(v, off, 64);
  return v;
}

// ---- K1: 1024 blocks (4/CU). All: softmax-sum partial (M=0) + attn_W proj.
//      blocks 0..255 also: ghh2 = W_hh@h + b + W_ih[:,0:40]@emb,
//                          transpose W_ih[:,40:50] -> WcT.
//      blocks 256..271 also: warm L3 with head weights.
__global__ __launch_bounds__(256, 4) void k1_attn(
    const float* __restrict__ E, const float* __restrict__ h,
    const float* __restrict__ attn_W, const float* __restrict__ W_hh,
    const float* __restrict__ b_ih, const float* __restrict__ b_hh,
    const float* __restrict__ W_ih,
    const float* __restrict__ chord_emb, const float* __restrict__ pitch_emb,
    const float* __restrict__ dur_emb,
    const int* __restrict__ sec_p, const int* __restrict__ chord_p,
    const int* __restrict__ note_p,
    const float* __restrict__ pitch_W, const float* __restrict__ dur_W,
    float* __restrict__ p10, float* __restrict__ ghh2,
    float* __restrict__ WcT, float* __restrict__ dummy) {
  const int b = blockIdx.x;
  const int t = threadIdx.x;
  const int lane = t & 63;
  const int w = t >> 6;
  const float4 hreg = reinterpret_cast<const float4*>(h)[lane];

  // ---- attention chunk: fixed M=0 exp-sum, 8-row unroll ----
  float s = 0.f;
  float4 acc = make_float4(0.f, 0.f, 0.f, 0.f);
  const float4* E4 = reinterpret_cast<const float4*>(E);
  const size_t base = (size_t)b * RPB;
#pragma unroll
  for (int k = 0; k < RPB / 32; ++k) {
    const int r = w * 8 + 32 * k;
    float4 e[8];
#pragma unroll
    for (int j = 0; j < 8; ++j) e[j] = E4[(base + r + j) * 64 + lane];
    float d[8];
#pragma unroll
    for (int j = 0; j < 8; ++j)
      d[j] = e[j].x * hreg.x + e[j].y * hreg.y + e[j].z * hreg.z + e[j].w * hreg.w;
#pragma unroll
    for (int off = 32; off > 0; off >>= 1) {
#pragma unroll
      for (int j = 0; j < 8; ++j) d[j] += __shfl_xor(d[j], off, 64);
    }
#pragma unroll
    for (int j = 0; j < 8; ++j) {
      const float wj = __expf(d[j]);
      s += wj;
      acc.x += wj * e[j].x;
      acc.y += wj * e[j].y;
      acc.z += wj * e[j].z;
      acc.w += wj * e[j].w;
    }
  }
  __shared__ float ss[4];
  __shared__ float4 sacc4[4][64];
  sacc4[w][lane] = acc;
  if (lane == 0) ss[w] = s;
  __syncthreads();
  __shared__ float ctx_s[H];
  {
    const float* sf = reinterpret_cast<const float*>(sacc4);
    ctx_s[t] = (sf[t] + sf[256 + t]) + (sf[512 + t] + sf[768 + t]);
  }
  __syncthreads();
  {
    const float4 c4 = reinterpret_cast<const float4*>(ctx_s)[lane];
    for (int row = w; row < 10; row += 4) {
      const float4 a4 = reinterpret_cast<const float4*>(attn_W + row * H)[lane];
      float d = c4.x * a4.x + c4.y * a4.y + c4.z * a4.z + c4.w * a4.w;
      d = wave_reduce_sum(d);
      if (lane == 0) p10[row * NBLK + b] = d;
    }
  }
  if (t == 0) p10[10 * NBLK + b] = (ss[0] + ss[1]) + (ss[2] + ss[3]);

  // ---- side work (hides in the drain phase) ----
  if (b < 256) {
    const int r = b * 4 + w;  // gate row
    const float4 wv = reinterpret_cast<const float4*>(W_hh + (size_t)r * H)[lane];
    float d = wv.x * hreg.x + wv.y * hreg.y + wv.z * hreg.z + wv.w * hreg.w;
    if (lane < 50) {
      const float wih = W_ih[r * 50 + lane];
      if (lane < 40) {
        int idx; const float* tbl;
        if (lane < 10)      { tbl = pitch_emb; idx = note_p[0] * 10 + lane; }
        else if (lane < 20) { tbl = dur_emb;   idx = note_p[1] * 10 + lane - 10; }
        else if (lane < 30) { tbl = chord_emb; idx = chord_p[0] * 10 + lane - 20; }
        else                { tbl = chord_emb; idx = sec_p[0] * 10 + lane - 30; }
        d += wih * tbl[idx];
      } else {
        WcT[(lane - 40) * GROWS + r] = wih;  // transpose cols 40..49
      }
    }
    d = wave_reduce_sum(d);
    if (lane == 0) ghh2[r] = d + b_ih[r] + b_hh[r];
  } else if (b < 272) {
    const int slice = b - 256;  // warm L3 for the tail
    float a = 0.f;
    const float4* pw4 = reinterpret_cast<const float4*>(pitch_W);
    for (int i = slice * 256 + t; i < 4032; i += 16 * 256) {
      float4 v = pw4[i]; a += v.x + v.y + v.z + v.w;
    }
    const float4* dw4 = reinterpret_cast<const float4*>(dur_W);
    for (int i = slice * 256 + t; i < 1064; i += 16 * 256) {
      float4 v = dw4[i]; a += v.x + v.y + v.z + v.w;
    }
    a = wave_reduce_sum(a);
    if (lane == 0) dummy[slice * 4 + w] = a;
  }
}

// ---- K2: fused tail, 4 blocks x 1024 thr, ISSUE-ALL-LOADS-FIRST form.
//      One memory latency for all inputs, then barrier-to-barrier compute.
__global__ __launch_bounds__(1024) void k2_tail(
    const float* __restrict__ p10, const float* __restrict__ ghh2,
    const float* __restrict__ WcT, const float* __restrict__ attn_b,
    const float* __restrict__ c_in,
    const float* __restrict__ pitch_W, const float* __restrict__ pitch_b,
    const float* __restrict__ dur_W, const float* __restrict__ dur_b,
    const float* __restrict__ pitch_emb, const int* __restrict__ tp_p,
    float* __restrict__ out) {
  const int t = threadIdx.x;
  const int lane = t & 63, w = t >> 6;   // 16 waves
  const int gw = blockIdx.x * 16 + w;    // 64 global waves

  // ======== EARLY ISSUE: every global read, no barriers in between ========
  // (a) p10 columns (waves 0..10): 1024 floats per column
  float4 pa0, pa1, pa2, pa3;
  if (w < 11) {
    const float4* pc = reinterpret_cast<const float4*>(p10 + w * NBLK);
    pa0 = pc[lane]; pa1 = pc[lane + 64]; pa2 = pc[lane + 128]; pa3 = pc[lane + 192];
  }
  // (b) gate inputs for row t
  const float g0 = ghh2[t];
  float wct[10];
#pragma unroll
  for (int c = 0; c < 10; ++c) wct[c] = WcT[c * GROWS + t];
  // (c) LSTM cell input
  const float cin = c_in[t & (H - 1)];
  // (d) pitch head row gw
  float4 pw4 = make_float4(0.f, 0.f, 0.f, 0.f);
  float pb = 0.f;
  if (gw < 63) {
    pw4 = reinterpret_cast<const float4*>(pitch_W + (size_t)gw * H)[lane];
    pb = pitch_b[gw];
  }
  // (e) dur head row gw-48 (block 3): 266 elems -> 5 per lane
  float dwr[5] = {0.f, 0.f, 0.f, 0.f, 0.f};
  float db = 0.f;
  if (gw >= 48) {
    const float* dwp = dur_W + (size_t)(gw - 48) * 266;
#pragma unroll
    for (int i = 0; i < 5; ++i) {
      const int k = lane + 64 * i;
      if (k < 266) dwr[i] = dwp[k];
    }
    db = dur_b[gw - 48];
  }
  // (f) e_true + attn bias
  const float et = (t < 10) ? pitch_emb[tp_p[0] * 10 + t] : 0.f;
  const float ab = (t < 10) ? attn_b[t] : 0.f;

  // ======== compute phases (registers/LDS only) ========
  __shared__ float red[11];
  __shared__ float ctxsh[10];
  __shared__ float gsh[1024];
  __shared__ float hsh[H];
  __shared__ float etsh[16];
  if (w < 11) {
    float v = (pa0.x + pa0.y + pa0.z + pa0.w) + (pa1.x + pa1.y + pa1.z + pa1.w) +
              (pa2.x + pa2.y + pa2.z + pa2.w) + (pa3.x + pa3.y + pa3.z + pa3.w);
    v = wave_reduce_sum(v);
    if (lane == 0) red[w] = v;
  }
  if (t < 10) etsh[t] = et;
  __syncthreads();
  if (t < 10) ctxsh[t] = red[t] / red[10] + ab;
  __syncthreads();
  float g = g0;
#pragma unroll
  for (int c = 0; c < 10; ++c) g += wct[c] * ctxsh[c];
  gsh[t] = g;
  __syncthreads();
  if (t < H) {
    const float i_s = 1.f / (1.f + __expf(-gsh[t]));
    const float f_s = 1.f / (1.f + __expf(-gsh[256 + t]));
    const float g_t = tanhf(gsh[512 + t]);
    const float o_s = 1.f / (1.f + __expf(-gsh[768 + t]));
    const float cn = f_s * cin + i_s * g_t;
    const float hn = o_s * tanhf(cn);
    if (blockIdx.x == 0) {
      out[79 + t] = hn;   // h_new at [79, 335)
      out[335 + t] = cn;  // c_new at [335, 591)
    }
    hsh[t] = hn;
  }
  __syncthreads();
  const float4 h4 = reinterpret_cast<const float4*>(hsh)[lane];
  if (gw < 63) {  // pitch head row gw
    float d = pw4.x * h4.x + pw4.y * h4.y + pw4.z * h4.z + pw4.w * h4.w;
    d = wave_reduce_sum(d);
    if (lane == 0) out[gw] = d + pb;
  }
  if (gw >= 48) {  // dur head row gw-48 over concat([e_true, h])
    float d = 0.f;
#pragma unroll
    for (int i = 0; i < 5; ++i) {
      const int k = lane + 64 * i;
      if (k < 266) d += dwr[i] * (k < 10 ? etsh[k] : hsh[k - 10]);
    }
    d = wave_reduce_sum(d);
    if (lane == 0) out[63 + (gw - 48)] = d + db;
  }
}

extern "C" void kernel_launch(void* const* d_in, const int* in_sizes, int n_in,
                              void* d_out, int out_size, void* d_ws, size_t ws_size,
                              hipStream_t stream) {
  const int* sec       = (const int*)d_in[0];
  const int* chord     = (const int*)d_in[1];
  const int* tp        = (const int*)d_in[2];
  const int* note      = (const int*)d_in[3];
  const float* hn      = (const float*)d_in[4];
  const float* cn      = (const float*)d_in[5];
  const float* E       = (const float*)d_in[6];
  const float* chord_e = (const float*)d_in[7];
  const float* pitch_e = (const float*)d_in[8];
  const float* dur_e   = (const float*)d_in[9];
  const float* W_ih    = (const float*)d_in[10];
  const float* W_hh    = (const float*)d_in[11];
  const float* b_ih    = (const float*)d_in[12];
  const float* b_hh    = (const float*)d_in[13];
  const float* pitch_W = (const float*)d_in[14];
  const float* pitch_b = (const float*)d_in[15];
  const float* dur_W   = (const float*)d_in[16];
  const float* dur_b   = (const float*)d_in[17];
  const float* attn_W  = (const float*)d_in[18];
  const float* attn_b  = (const float*)d_in[19];
  float* out = (float*)d_out;
  float* ws = (float*)d_ws;

  float* p10   = ws;                  // 11 * NBLK
  float* ghh2  = ws + 11 * NBLK;      // 1024
  float* WcT   = ghh2 + GROWS;        // 10 * 1024
  float* dummy = WcT + 10 * GROWS;    // 64

  k1_attn<<<NBLK, 256, 0, stream>>>(E, hn, attn_W, W_hh, b_ih, b_hh, W_ih,
                                    chord_e, pitch_e, dur_e, sec, chord, note,
                                    pitch_W, dur_W, p10, ghh2, WcT, dummy);
  k2_tail<<<4, 1024, 0, stream>>>(p10, ghh2, WcT, attn_b, cn,
                                  pitch_W, pitch_b, dur_W, dur_b,
                                  pitch_e, tp, out);
}

// Round 11
// 30.208 us; speedup vs baseline: 2.6177x; 1.0014x over previous
//
#include <hip/hip_runtime.h>
#include <hip/hip_bf16.h>
#include <math.h>

#define H 256
#define L_SEQ 131072
#define NBLK 1024           // attention blocks
#define RPB (L_SEQ / NBLK)  // 128 rows per block
#define GROWS 1024          // LSTM gate rows (4H)

typedef __attribute__((ext_vector_type(4))) float f32x4;

__device__ __forceinline__ float wave_reduce_sum(float v) {
#pragma unroll
  for (int off = 32; off > 0; off >>= 1) v += __shfl_xor(v, off, 64);
  return v;
}

// ---- K1: 1024 blocks (4/CU). 16-lane-group attention scan.
//      Lane = (group g = lane>>4, col-lane cl = lane&15). Group handles one
//      row per iter; lane covers cols cl*4 + 64k, k=0..3. 4-step width-16
//      butterfly reduces the dot for 4 rows at once; 1 exp per lane.
//      blocks 0..255 also: ghh2 = W_hh@h + b + W_ih[:,0:40]@emb, WcT transpose.
//      blocks 256..271 also: warm L3 with head weights.
__global__ __launch_bounds__(256, 4) void k1_attn(
    const float* __restrict__ E, const float* __restrict__ h,
    const float* __restrict__ attn_W, const float* __restrict__ W_hh,
    const float* __restrict__ b_ih, const float* __restrict__ b_hh,
    const float* __restrict__ W_ih,
    const float* __restrict__ chord_emb, const float* __restrict__ pitch_emb,
    const float* __restrict__ dur_emb,
    const int* __restrict__ sec_p, const int* __restrict__ chord_p,
    const int* __restrict__ note_p,
    const float* __restrict__ pitch_W, const float* __restrict__ dur_W,
    float* __restrict__ p10, float* __restrict__ ghh2,
    float* __restrict__ WcT, float* __restrict__ dummy) {
  const int b = blockIdx.x;
  const int t = threadIdx.x;
  const int lane = t & 63;
  const int w = t >> 6;
  const int cl = lane & 15;   // column-lane within group
  const int g  = lane >> 4;   // group 0..3

  const f32x4* E4 = reinterpret_cast<const f32x4*>(E);
  const f32x4* h4 = reinterpret_cast<const f32x4*>(h);

  // h fragments for this lane's columns (cl*4 + 64k)
  f32x4 hk[4];
#pragma unroll
  for (int k = 0; k < 4; ++k) hk[k] = h4[cl + 16 * k];

  const f32x4 vzero = {0.f, 0.f, 0.f, 0.f};
  f32x4 acc[4];
#pragma unroll
  for (int k = 0; k < 4; ++k) acc[k] = vzero;
  float s = 0.f;

  // rows: wave w covers rows [w*32, w*32+32); iter i: group g owns row
  // base + w*32 + i*4 + g. Per iter each lane loads 4 f32x4 (64B).
  const size_t base = (size_t)b * RPB;
  size_t off = (base + (size_t)w * 32 + g) * 64 + cl;  // f32x4 units

  f32x4 eA[4], eB[4];
#pragma unroll
  for (int k = 0; k < 4; ++k) eA[k] = E4[off + 16 * k];
#pragma unroll
  for (int i = 0; i < 8; ++i) {
    const f32x4* cur = (i & 1) ? eB : eA;
    f32x4* nxt = (i & 1) ? eA : eB;
    if (i < 7) {  // prefetch next round before compute
      const size_t o2 = off + 256 * (size_t)(i + 1);
#pragma unroll
      for (int k = 0; k < 4; ++k) nxt[k] = E4[o2 + 16 * k];
    }
    float d = 0.f;
#pragma unroll
    for (int k = 0; k < 4; ++k)
      d += cur[k].x * hk[k].x + cur[k].y * hk[k].y +
           cur[k].z * hk[k].z + cur[k].w * hk[k].w;
    d += __shfl_xor(d, 1, 16);
    d += __shfl_xor(d, 2, 16);
    d += __shfl_xor(d, 4, 16);
    d += __shfl_xor(d, 8, 16);
    const float wj = __expf(d);
    s += wj;
#pragma unroll
    for (int k = 0; k < 4; ++k) acc[k] += wj * cur[k];
  }

  // ---- combine group partials: LDS [wave][group][cl][k] (16 KB) ----
  __shared__ float ss[4];
  __shared__ f32x4 sacc[4][4][16][4];
#pragma unroll
  for (int k = 0; k < 4; ++k) sacc[w][g][cl][k] = acc[k];
  {
    const float sw = wave_reduce_sum(s) * 0.0625f;  // /16: replicated in group
    if (lane == 0) ss[w] = sw;
  }
  __syncthreads();
  __shared__ float ctx_s[H];
  {
    // thread t -> column t: k = t>>6, cc = (t>>2)&15, j = t&3
    const int k = t >> 6, cc = (t >> 2) & 15, j = t & 3;
    float v = 0.f;
#pragma unroll
    for (int ww = 0; ww < 4; ++ww)
#pragma unroll
      for (int gg = 0; gg < 4; ++gg)
        v += reinterpret_cast<const float*>(&sacc[ww][gg][cc][k])[j];
    ctx_s[t] = v;
  }
  __syncthreads();
  {
    const float4 c4 = reinterpret_cast<const float4*>(ctx_s)[lane];
    for (int row = w; row < 10; row += 4) {
      const float4 a4 = reinterpret_cast<const float4*>(attn_W + row * H)[lane];
      float d = c4.x * a4.x + c4.y * a4.y + c4.z * a4.z + c4.w * a4.w;
      d = wave_reduce_sum(d);
      if (lane == 0) p10[row * NBLK + b] = d;
    }
  }
  if (t == 0) p10[10 * NBLK + b] = (ss[0] + ss[1]) + (ss[2] + ss[3]);

  // ---- side work (hides in the drain phase) ----
  const float4 hreg = reinterpret_cast<const float4*>(h)[lane];
  if (b < 256) {
    const int r = b * 4 + w;  // gate row
    const float4 wv = reinterpret_cast<const float4*>(W_hh + (size_t)r * H)[lane];
    float d = wv.x * hreg.x + wv.y * hreg.y + wv.z * hreg.z + wv.w * hreg.w;
    if (lane < 50) {
      const float wih = W_ih[r * 50 + lane];
      if (lane < 40) {
        int idx; const float* tbl;
        if (lane < 10)      { tbl = pitch_emb; idx = note_p[0] * 10 + lane; }
        else if (lane < 20) { tbl = dur_emb;   idx = note_p[1] * 10 + lane - 10; }
        else if (lane < 30) { tbl = chord_emb; idx = chord_p[0] * 10 + lane - 20; }
        else                { tbl = chord_emb; idx = sec_p[0] * 10 + lane - 30; }
        d += wih * tbl[idx];
      } else {
        WcT[(lane - 40) * GROWS + r] = wih;  // transpose cols 40..49
      }
    }
    d = wave_reduce_sum(d);
    if (lane == 0) ghh2[r] = d + b_ih[r] + b_hh[r];
  } else if (b < 272) {
    const int slice = b - 256;  // warm L3 for the tail
    float a = 0.f;
    const float4* pw4 = reinterpret_cast<const float4*>(pitch_W);
    for (int i = slice * 256 + t; i < 4032; i += 16 * 256) {
      float4 v = pw4[i]; a += v.x + v.y + v.z + v.w;
    }
    const float4* dw4 = reinterpret_cast<const float4*>(dur_W);
    for (int i = slice * 256 + t; i < 1064; i += 16 * 256) {
      float4 v = dw4[i]; a += v.x + v.y + v.z + v.w;
    }
    a = wave_reduce_sum(a);
    if (lane == 0) dummy[slice * 4 + w] = a;
  }
}

// ---- K2: fused tail, 4 blocks x 1024 thr, ISSUE-ALL-LOADS-FIRST form. ----
__global__ __launch_bounds__(1024) void k2_tail(
    const float* __restrict__ p10, const float* __restrict__ ghh2,
    const float* __restrict__ WcT, const float* __restrict__ attn_b,
    const float* __restrict__ c_in,
    const float* __restrict__ pitch_W, const float* __restrict__ pitch_b,
    const float* __restrict__ dur_W, const float* __restrict__ dur_b,
    const float* __restrict__ pitch_emb, const int* __restrict__ tp_p,
    float* __restrict__ out) {
  const int t = threadIdx.x;
  const int lane = t & 63, w = t >> 6;   // 16 waves
  const int gw = blockIdx.x * 16 + w;    // 64 global waves

  // ======== EARLY ISSUE: every global read, no barriers in between ========
  float4 pa0, pa1, pa2, pa3;
  if (w < 11) {
    const float4* pc = reinterpret_cast<const float4*>(p10 + w * NBLK);
    pa0 = pc[lane]; pa1 = pc[lane + 64]; pa2 = pc[lane + 128]; pa3 = pc[lane + 192];
  }
  const float g0 = ghh2[t];
  float wct[10];
#pragma unroll
  for (int c = 0; c < 10; ++c) wct[c] = WcT[c * GROWS + t];
  const float cin = c_in[t & (H - 1)];
  float4 pw4 = make_float4(0.f, 0.f, 0.f, 0.f);
  float pb = 0.f;
  if (gw < 63) {
    pw4 = reinterpret_cast<const float4*>(pitch_W + (size_t)gw * H)[lane];
    pb = pitch_b[gw];
  }
  float dwr[5] = {0.f, 0.f, 0.f, 0.f, 0.f};
  float db = 0.f;
  if (gw >= 48) {
    const float* dwp = dur_W + (size_t)(gw - 48) * 266;
#pragma unroll
    for (int i = 0; i < 5; ++i) {
      const int k = lane + 64 * i;
      if (k < 266) dwr[i] = dwp[k];
    }
    db = dur_b[gw - 48];
  }
  const float et = (t < 10) ? pitch_emb[tp_p[0] * 10 + t] : 0.f;
  const float ab = (t < 10) ? attn_b[t] : 0.f;

  // ======== compute phases (registers/LDS only) ========
  __shared__ float red[11];
  __shared__ float ctxsh[10];
  __shared__ float gsh[1024];
  __shared__ float hsh[H];
  __shared__ float etsh[16];
  if (w < 11) {
    float v = (pa0.x + pa0.y + pa0.z + pa0.w) + (pa1.x + pa1.y + pa1.z + pa1.w) +
              (pa2.x + pa2.y + pa2.z + pa2.w) + (pa3.x + pa3.y + pa3.z + pa3.w);
    v = wave_reduce_sum(v);
    if (lane == 0) red[w] = v;
  }
  if (t < 10) etsh[t] = et;
  __syncthreads();
  if (t < 10) ctxsh[t] = red[t] / red[10] + ab;
  __syncthreads();
  float g = g0;
#pragma unroll
  for (int c = 0; c < 10; ++c) g += wct[c] * ctxsh[c];
  gsh[t] = g;
  __syncthreads();
  if (t < H) {
    const float i_s = 1.f / (1.f + __expf(-gsh[t]));
    const float f_s = 1.f / (1.f + __expf(-gsh[256 + t]));
    const float g_t = tanhf(gsh[512 + t]);
    const float o_s = 1.f / (1.f + __expf(-gsh[768 + t]));
    const float cn = f_s * cin + i_s * g_t;
    const float hn = o_s * tanhf(cn);
    if (blockIdx.x == 0) {
      out[79 + t] = hn;   // h_new at [79, 335)
      out[335 + t] = cn;  // c_new at [335, 591)
    }
    hsh[t] = hn;
  }
  __syncthreads();
  const float4 h4 = reinterpret_cast<const float4*>(hsh)[lane];
  if (gw < 63) {  // pitch head row gw
    float d = pw4.x * h4.x + pw4.y * h4.y + pw4.z * h4.z + pw4.w * h4.w;
    d = wave_reduce_sum(d);
    if (lane == 0) out[gw] = d + pb;
  }
  if (gw >= 48) {  // dur head row gw-48 over concat([e_true, h])
    float d = 0.f;
#pragma unroll
    for (int i = 0; i < 5; ++i) {
      const int k = lane + 64 * i;
      if (k < 266) d += dwr[i] * (k < 10 ? etsh[k] : hsh[k - 10]);
    }
    d = wave_reduce_sum(d);
    if (lane == 0) out[63 + (gw - 48)] = d + db;
  }
}

extern "C" void kernel_launch(void* const* d_in, const int* in_sizes, int n_in,
                              void* d_out, int out_size, void* d_ws, size_t ws_size,
                              hipStream_t stream) {
  const int* sec       = (const int*)d_in[0];
  const int* chord     = (const int*)d_in[1];
  const int* tp        = (const int*)d_in[2];
  const int* note      = (const int*)d_in[3];
  const float* hn      = (const float*)d_in[4];
  const float* cn      = (const float*)d_in[5];
  const float* E       = (const float*)d_in[6];
  const float* chord_e = (const float*)d_in[7];
  const float* pitch_e = (const float*)d_in[8];
  const float* dur_e   = (const float*)d_in[9];
  const float* W_ih    = (const float*)d_in[10];
  const float* W_hh    = (const float*)d_in[11];
  const float* b_ih    = (const float*)d_in[12];
  const float* b_hh    = (const float*)d_in[13];
  const float* pitch_W = (const float*)d_in[14];
  const float* pitch_b = (const float*)d_in[15];
  const float* dur_W   = (const float*)d_in[16];
  const float* dur_b   = (const float*)d_in[17];
  const float* attn_W  = (const float*)d_in[18];
  const float* attn_b  = (const float*)d_in[19];
  float* out = (float*)d_out;
  float* ws = (float*)d_ws;

  float* p10   = ws;                  // 11 * NBLK
  float* ghh2  = ws + 11 * NBLK;      // 1024
  float* WcT   = ghh2 + GROWS;        // 10 * 1024
  float* dummy = WcT + 10 * GROWS;    // 64

  k1_attn<<<NBLK, 256, 0, stream>>>(E, hn, attn_W, W_hh, b_ih, b_hh, W_ih,
                                    chord_e, pitch_e, dur_e, sec, chord, note,
                                    pitch_W, dur_W, p10, ghh2, WcT, dummy);
  k2_tail<<<4, 1024, 0, stream>>>(p10, ghh2, WcT, attn_b, cn,
                                  pitch_W, pitch_b, dur_W, dur_b,
                                  pitch_e, tp, out);
}